// Round 1
// baseline (2249.600 us; speedup 1.0000x reference)
//
#include <hip/hip_runtime.h>
#include <cstddef>

// ---------------------------------------------------------------------------
// RQ-VAE forward, fp32 throughout (argmin decisions are precision-critical:
// bf16-level error flips codebook argmins -> O(1) absmax errors in y).
// ---------------------------------------------------------------------------

#define BM 128
#define BN 128
#define BK 16

// C = act(A @ W + bias)
// A: M x K row-major.
// W: K x N row-major, or (TRANSW) W is N x K row-major (codebook: scores = A @ W^T).
template<bool RELU, bool TRANSW, bool HASBIAS>
__global__ __launch_bounds__(256, 2)
void sgemm_kernel(const float* __restrict__ A, const float* __restrict__ W,
                  const float* __restrict__ bias, float* __restrict__ C,
                  int M, int N, int K)
{
    __shared__ float As[BK][BM + 4];   // +4 pad: transposed stores conflict-free
    __shared__ float Ws[BK][BN + 4];

    const int tid = threadIdx.x;
    const int tx  = tid & 15;          // 0..15 -> n
    const int ty  = tid >> 4;          // 0..15 -> m
    const long bm = (long)blockIdx.x * BM;
    const long bn = (long)blockIdx.y * BN;

    float acc[2][2][4][4] = {};

    for (int k0 = 0; k0 < K; k0 += BK) {
        // ---- stage A tile (128 rows x 16 k), store transposed As[k][m]
        #pragma unroll
        for (int i = 0; i < 2; i++) {
            int idx = tid + i * 256;           // 0..511
            int row = idx >> 2;                // 0..127
            int kc  = (idx & 3) << 2;          // 0,4,8,12
            float4 a = *reinterpret_cast<const float4*>(A + (bm + row) * (long)K + k0 + kc);
            As[kc + 0][row] = a.x; As[kc + 1][row] = a.y;
            As[kc + 2][row] = a.z; As[kc + 3][row] = a.w;
        }
        // ---- stage W tile (16 k x 128 n)
        if constexpr (!TRANSW) {
            #pragma unroll
            for (int i = 0; i < 2; i++) {
                int idx = tid + i * 256;
                int kr  = idx >> 5;            // 0..15
                int nc  = (idx & 31) << 2;     // 0..124
                float4 w = *reinterpret_cast<const float4*>(W + (long)(k0 + kr) * N + bn + nc);
                *reinterpret_cast<float4*>(&Ws[kr][nc]) = w;
            }
        } else {
            // W is [N][K] (codebook rows); read rows, scatter transposed.
            #pragma unroll
            for (int i = 0; i < 2; i++) {
                int idx  = tid + i * 256;
                int nrow = idx >> 2;           // 0..127
                int kc   = (idx & 3) << 2;
                float4 w = *reinterpret_cast<const float4*>(W + (bn + nrow) * (long)K + k0 + kc);
                Ws[kc + 0][nrow] = w.x; Ws[kc + 1][nrow] = w.y;
                Ws[kc + 2][nrow] = w.z; Ws[kc + 3][nrow] = w.w;
            }
        }
        __syncthreads();

        #pragma unroll
        for (int k = 0; k < BK; k++) {
            float4 a0 = *reinterpret_cast<const float4*>(&As[k][ty * 4]);
            float4 a1 = *reinterpret_cast<const float4*>(&As[k][64 + ty * 4]);
            float4 b0 = *reinterpret_cast<const float4*>(&Ws[k][tx * 4]);
            float4 b1 = *reinterpret_cast<const float4*>(&Ws[k][64 + tx * 4]);
            float av[2][4] = {{a0.x, a0.y, a0.z, a0.w}, {a1.x, a1.y, a1.z, a1.w}};
            float bv[2][4] = {{b0.x, b0.y, b0.z, b0.w}, {b1.x, b1.y, b1.z, b1.w}};
            #pragma unroll
            for (int im = 0; im < 2; im++)
                #pragma unroll
                for (int in = 0; in < 2; in++)
                    #pragma unroll
                    for (int i = 0; i < 4; i++)
                        #pragma unroll
                        for (int j = 0; j < 4; j++)
                            acc[im][in][i][j] = fmaf(av[im][i], bv[in][j], acc[im][in][i][j]);
        }
        __syncthreads();
    }

    #pragma unroll
    for (int im = 0; im < 2; im++)
        #pragma unroll
        for (int i = 0; i < 4; i++) {
            long row = bm + im * 64 + ty * 4 + i;
            #pragma unroll
            for (int in = 0; in < 2; in++) {
                long col = bn + in * 64 + tx * 4;
                float4 v;
                v.x = acc[im][in][i][0]; v.y = acc[im][in][i][1];
                v.z = acc[im][in][i][2]; v.w = acc[im][in][i][3];
                if constexpr (HASBIAS) {
                    float4 b = *reinterpret_cast<const float4*>(bias + col);
                    v.x += b.x; v.y += b.y; v.z += b.z; v.w += b.w;
                }
                if constexpr (RELU) {
                    v.x = fmaxf(v.x, 0.f); v.y = fmaxf(v.y, 0.f);
                    v.z = fmaxf(v.z, 0.f); v.w = fmaxf(v.w, 0.f);
                }
                *reinterpret_cast<float4*>(C + row * (long)N + col) = v;
            }
        }
}

// Per-row argmin over 256 codes + residual/x_q update + SSE accumulation.
// dist_j = ||r||^2 - 2 r.C_j + ||C_j||^2 ; argmin ignores ||r||^2.
// One wave per row; lane l owns codes {l, l+64, l+128, l+192} (ascending ->
// first-occurrence tie-break like jnp.argmin).
__global__ __launch_bounds__(256)
void rq_update_kernel(const float* __restrict__ scores,  // [M][256] = r.C_j
                      const float* __restrict__ cb,      // [256][128]
                      const float* __restrict__ src,     // z (level 0) or resid
                      float* __restrict__ resid,
                      float* __restrict__ xq,
                      float* __restrict__ lossF,         // accumulator for this level
                      int M, int first)
{
    __shared__ float c2s[256];
    __shared__ float lsum[4];
    const int tid  = threadIdx.x;
    const int lane = tid & 63;
    const int wave = tid >> 6;

    {   // ||C_j||^2, once per block
        float s = 0.f;
        #pragma unroll
        for (int d = 0; d < 128; d += 4) {
            float4 v = *reinterpret_cast<const float4*>(cb + (long)tid * 128 + d);
            s += v.x * v.x + v.y * v.y + v.z * v.z + v.w * v.w;
        }
        c2s[tid] = s;
    }
    __syncthreads();

    float myloss = 0.f;
    const int stride = gridDim.x * 4;
    for (int row = blockIdx.x * 4 + wave; row < M; row += stride) {
        const float* srow = scores + (long)row * 256;
        float best = 3.4e38f; int bidx = 0;
        #pragma unroll
        for (int j = 0; j < 4; j++) {
            int code = lane + j * 64;
            float d = fmaf(-2.f, srow[code], c2s[code]);
            if (d < best) { best = d; bidx = code; }
        }
        #pragma unroll
        for (int off = 32; off > 0; off >>= 1) {
            float ob = __shfl_down(best, off);
            int   oi = __shfl_down(bidx, off);
            if (ob < best || (ob == best && oi < bidx)) { best = ob; bidx = oi; }
        }
        bidx = __shfl(bidx, 0);

        long base = (long)row * 128 + lane * 2;
        float2 r = *reinterpret_cast<const float2*>(src + base);
        float2 q = *reinterpret_cast<const float2*>(cb + (long)bidx * 128 + lane * 2);
        float dx = r.x - q.x, dy = r.y - q.y;
        myloss += dx * dx + dy * dy;
        float2 nr; nr.x = dx; nr.y = dy;
        *reinterpret_cast<float2*>(resid + base) = nr;
        if (first) {
            float2 qv; qv.x = q.x; qv.y = q.y;
            *reinterpret_cast<float2*>(xq + base) = qv;
        } else {
            float2 xv = *reinterpret_cast<float2*>(xq + base);
            xv.x += q.x; xv.y += q.y;
            *reinterpret_cast<float2*>(xq + base) = xv;
        }
    }

    #pragma unroll
    for (int off = 32; off > 0; off >>= 1) myloss += __shfl_down(myloss, off);
    if (lane == 0) lsum[wave] = myloss;
    __syncthreads();
    if (tid == 0) atomicAdd(lossF, (lsum[0] + lsum[1]) + (lsum[2] + lsum[3]));
}

__global__ void zero4_kernel(float* __restrict__ F)
{
    if (threadIdx.x < 4) F[threadIdx.x] = 0.f;
}

// rq_loss = mean_l [ 1.25 * SSE_l / (M*128) ]
__global__ void finalize_loss_kernel(const float* __restrict__ F, float* __restrict__ out)
{
    if (threadIdx.x == 0) {
        float s = (F[0] + F[1]) + (F[2] + F[3]);
        out[0] = s * (1.25f / (4.f * 65536.f * 128.f));
    }
}

extern "C" void kernel_launch(void* const* d_in, const int* in_sizes, int n_in,
                              void* d_out, int out_size, void* d_ws, size_t ws_size,
                              hipStream_t stream)
{
    const float* x      = (const float*)d_in[0];
    const float* enc_w0 = (const float*)d_in[1];
    const float* enc_b0 = (const float*)d_in[2];
    const float* enc_w1 = (const float*)d_in[3];
    const float* enc_b1 = (const float*)d_in[4];
    const float* enc_w2 = (const float*)d_in[5];
    const float* enc_b2 = (const float*)d_in[6];
    const float* dec_w0 = (const float*)d_in[7];
    const float* dec_b0 = (const float*)d_in[8];
    const float* dec_w1 = (const float*)d_in[9];
    const float* dec_b1 = (const float*)d_in[10];
    const float* dec_w2 = (const float*)d_in[11];
    const float* dec_b2 = (const float*)d_in[12];
    const float* codebooks = (const float*)d_in[13];

    const int M = 65536;
    float* ws = (float*)d_ws;

    // Workspace overlay (total exactly 65536*768 floats = 201.3 MB):
    //   bufA [0, 33.5M): enc h1  ->  {z, resid, xq, F}  ->  dec h2
    //   bufB [33.5M, 50.3M): enc h2  ->  scores  ->  dec h1
    float* bufA   = ws;
    float* bufB   = ws + 33554432;
    float* z      = bufA;               // live: enc3 .. rq level 0
    float* resid  = bufA + 8388608;     // live: rq levels
    float* xq     = bufA + 16777216;    // live: rq .. dec1
    float* F      = bufA + 25165824;    // live: rq .. finalize (before dec2!)
    float* scores = bufB;
    float* y      = (float*)d_out;

    dim3 blk(256);

    zero4_kernel<<<dim3(1), dim3(64), 0, stream>>>(F);

    // ---- encoder
    sgemm_kernel<true,  false, true><<<dim3(512, 4), blk, 0, stream>>>(x,    enc_w0, enc_b0, bufA, M, 512, 768);
    sgemm_kernel<true,  false, true><<<dim3(512, 2), blk, 0, stream>>>(bufA, enc_w1, enc_b1, bufB, M, 256, 512);
    sgemm_kernel<false, false, true><<<dim3(512, 1), blk, 0, stream>>>(bufB, enc_w2, enc_b2, z,    M, 128, 256);

    // ---- residual quantization (4 sequential levels)
    for (int l = 0; l < 4; l++) {
        const float* cb  = codebooks + (long)l * 256 * 128;
        const float* src = (l == 0) ? z : resid;
        sgemm_kernel<false, true, false><<<dim3(512, 2), blk, 0, stream>>>(src, cb, nullptr, scores, M, 256, 128);
        rq_update_kernel<<<dim3(1024), blk, 0, stream>>>(scores, cb, src, resid, xq, F + l, M, (l == 0) ? 1 : 0);
    }

    // loss before dec2 clobbers bufA
    finalize_loss_kernel<<<dim3(1), dim3(64), 0, stream>>>(F, y + (long)M * 768);

    // ---- decoder (y_q == x_q numerically: z + sg(x_q - z))
    sgemm_kernel<true,  false, true><<<dim3(512, 2), blk, 0, stream>>>(xq,   dec_w0, dec_b0, bufB, M, 256, 128);
    sgemm_kernel<true,  false, true><<<dim3(512, 4), blk, 0, stream>>>(bufB, dec_w1, dec_b1, bufA, M, 512, 256);
    sgemm_kernel<false, false, true><<<dim3(512, 6), blk, 0, stream>>>(bufA, dec_w2, dec_b2, y,    M, 768, 512);
}

// Round 2
// 1264.485 us; speedup vs baseline: 1.7791x; 1.7791x over previous
//
#include <hip/hip_runtime.h>
#include <cstdint>
#include <cstddef>

// ---------------------------------------------------------------------------
// RQ-VAE forward. Matmuls on MFMA via 2-term f16 split (hi + lo*2048), three
// chains hh / h*lo / lo*h with a separate cross-accumulator (x 1/2048 at
// epilogue) so f16-subnormal lo values never hit potential MFMA denorm flush.
// Effective precision ~2^-22 relative: safe for the codebook argmins.
// Residual-quantization bookkeeping (argmin, residuals, loss) stays fp32.
// ---------------------------------------------------------------------------

typedef _Float16 F16;
typedef F16  v8h __attribute__((ext_vector_type(8)));
typedef float v4f __attribute__((ext_vector_type(4)));

__device__ __forceinline__ void gload_lds16(const void* g, void* l) {
    __builtin_amdgcn_global_load_lds(
        (const __attribute__((address_space(1))) void*)g,
        (__attribute__((address_space(3))) void*)l, 16, 0, 0);
}

__device__ __forceinline__ void split2(float v, F16& h, F16& l) {
    h = (F16)v;
    l = (F16)((v - (float)h) * 2048.0f);   // lo scaled to normal f16 range
}

// C = act(A @ B^T_split + bias). A: M x K fp32 (split in-kernel).
// Bh/Bl: N x K f16 (pre-split, pre-transposed; Bl holds lo*2048).
// Tile 128x128, BK=32. 4 waves (2x2), each 64x64 = 4x4 frags of 16x16x32.
// LDS tiles: [row 0..127][chunk 0..7] of 16B; chunks 0-3 = hi k0..31,
// 4-7 = lo; physical chunk = logical ^ (row&7) (bank-conflict-free reads,
// and linear in lane order for global_load_lds).
template<bool RELU, bool HASBIAS>
__global__ __launch_bounds__(256, 2)
void f16gemm_kernel(const float* __restrict__ A, const F16* __restrict__ Bh,
                    const F16* __restrict__ Bl, const float* __restrict__ bias,
                    float* __restrict__ C, int M, int N, int K)
{
    __shared__ v8h As[1024];   // 16 KB
    __shared__ v8h Bs[1024];   // 16 KB

    const int tid  = threadIdx.x;
    const int lane = tid & 63;
    const int wid  = tid >> 6;
    const int wr   = wid >> 1;              // wave row (M)
    const int wc   = wid & 1;               // wave col (N)
    const long bm  = (long)blockIdx.x * 128;
    const long bn  = (long)blockIdx.y * 128;

    // ---- A staging assignment: row = tid&127, chunk = (tid>>7) + 2*i ----
    const int sm = tid & 127;
    const int sc = tid >> 7;
    const float* aSrc = A + (bm + sm) * (long)K + sc * 8;

    // ---- B global_load_lds: wave chunk j = wid*4+jj; lane -> (n, phys p) ----
    const int bc = (lane & 7) ^ (lane >> 3);   // logical chunk this lane fetches
    const F16* bSrcBase[4];
    void* bDst[4];
    #pragma unroll
    for (int jj = 0; jj < 4; jj++) {
        int j  = wid * 4 + jj;
        long n = bn + j * 8 + (lane >> 3);
        bSrcBase[jj] = (bc < 4) ? (Bh + n * (long)K + bc * 8)
                                : (Bl + n * (long)K + (bc - 4) * 8);
        bDst[jj] = (void*)(Bs + j * 64);
    }

    // ---- fragment read offsets (v8h units); lo buddy = offset ^ 4 ----
    const int cq = lane >> 4;               // k-group 0..3
    int aOff[4], bOff[4];
    #pragma unroll
    for (int i = 0; i < 4; i++) {
        int am  = wr * 64 + i * 16 + (lane & 15);
        aOff[i] = am * 8 + (cq ^ (am & 7));
        int bn2 = wc * 64 + i * 16 + (lane & 15);
        bOff[i] = bn2 * 8 + (cq ^ (bn2 & 7));
    }

    v4f acc[4][4]  = {};
    v4f accx[4][4] = {};

    for (int k0 = 0; k0 < K; k0 += 32) {
        #pragma unroll
        for (int jj = 0; jj < 4; jj++)
            gload_lds16(bSrcBase[jj] + k0, bDst[jj]);

        #pragma unroll
        for (int i = 0; i < 2; i++) {
            const float* s = aSrc + k0 + i * 16;
            float4 v0 = *reinterpret_cast<const float4*>(s);
            float4 v1 = *reinterpret_cast<const float4*>(s + 4);
            float vv[8] = {v0.x, v0.y, v0.z, v0.w, v1.x, v1.y, v1.z, v1.w};
            v8h hi, lo;
            #pragma unroll
            for (int e = 0; e < 8; e++) { F16 h, l; split2(vv[e], h, l); hi[e] = h; lo[e] = l; }
            int ph = (sc + 2 * i) ^ (sm & 7);
            As[sm * 8 + ph]       = hi;
            As[sm * 8 + (ph ^ 4)] = lo;
        }
        __syncthreads();

        v8h bh[4], bl[4];
        #pragma unroll
        for (int ni = 0; ni < 4; ni++) {
            bh[ni] = Bs[bOff[ni]];
            bl[ni] = Bs[bOff[ni] ^ 4];
        }
        #pragma unroll
        for (int mi = 0; mi < 4; mi++) {
            v8h ah = As[aOff[mi]];
            v8h al = As[aOff[mi] ^ 4];
            #pragma unroll
            for (int ni = 0; ni < 4; ni++) {
                acc[mi][ni]  = __builtin_amdgcn_mfma_f32_16x16x32_f16(ah, bh[ni], acc[mi][ni],  0, 0, 0);
                accx[mi][ni] = __builtin_amdgcn_mfma_f32_16x16x32_f16(ah, bl[ni], accx[mi][ni], 0, 0, 0);
                accx[mi][ni] = __builtin_amdgcn_mfma_f32_16x16x32_f16(al, bh[ni], accx[mi][ni], 0, 0, 0);
            }
        }
        __syncthreads();
    }

    // ---- epilogue: D = acc + accx/2048 + bias, optional relu, fp32 store ----
    const int rbase = (lane >> 4) * 4;
    const int cl    = lane & 15;
    #pragma unroll
    for (int ni = 0; ni < 4; ni++) {
        long col = bn + wc * 64 + ni * 16 + cl;
        float bv = 0.0f;
        if constexpr (HASBIAS) bv = bias[col];
        #pragma unroll
        for (int mi = 0; mi < 4; mi++) {
            #pragma unroll
            for (int r = 0; r < 4; r++) {
                long row = bm + wr * 64 + mi * 16 + rbase + r;
                float v = acc[mi][ni][r] + accx[mi][ni][r] * (1.0f / 2048.0f) + bv;
                if constexpr (RELU) v = fmaxf(v, 0.0f);
                C[row * (long)N + col] = v;
            }
        }
    }
}

// W: K x N fp32 -> H/L: N x K f16 split (transpose + split).
__global__ void wprep_kernel(const float* __restrict__ W, F16* __restrict__ H,
                             F16* __restrict__ L, int K, int N)
{
    int i = blockIdx.x * 256 + threadIdx.x;
    if (i >= K * N) return;
    int k = i / N, n = i % N;
    float v = W[i];
    F16 h, l; split2(v, h, l);
    H[(long)n * K + k] = h;
    L[(long)n * K + k] = l;
}

// codebooks already [level][n][k]-major: elementwise split. 4*256*128 = 131072.
__global__ void cbprep_kernel(const float* __restrict__ Cb, F16* __restrict__ H,
                              F16* __restrict__ L)
{
    int i = blockIdx.x * 256 + threadIdx.x;
    float v = Cb[i];
    F16 h, l; split2(v, h, l);
    H[i] = h; L[i] = l;
}

// Per-row argmin over 256 codes + residual/x_q update + SSE accumulation.
// One wave per row; lane l owns codes {l, l+64, l+128, l+192} (first-index
// tie-break like jnp.argmin). All fp32/exact.
__global__ __launch_bounds__(256)
void rq_update_kernel(const float* __restrict__ scores,  // [M][256] = r.C_j
                      const float* __restrict__ cb,      // [256][128] fp32
                      const float* __restrict__ src,     // z (level 0) or resid
                      float* __restrict__ resid,
                      float* __restrict__ xq,
                      float* __restrict__ lossF,
                      int M, int first)
{
    __shared__ float c2s[256];
    __shared__ float lsum[4];
    const int tid  = threadIdx.x;
    const int lane = tid & 63;
    const int wave = tid >> 6;

    {   float s = 0.f;
        #pragma unroll
        for (int d = 0; d < 128; d += 4) {
            float4 v = *reinterpret_cast<const float4*>(cb + (long)tid * 128 + d);
            s += v.x * v.x + v.y * v.y + v.z * v.z + v.w * v.w;
        }
        c2s[tid] = s;
    }
    __syncthreads();

    float myloss = 0.f;
    const int stride = gridDim.x * 4;
    for (int row = blockIdx.x * 4 + wave; row < M; row += stride) {
        const float* srow = scores + (long)row * 256;
        float best = 3.4e38f; int bidx = 0;
        #pragma unroll
        for (int j = 0; j < 4; j++) {
            int code = lane + j * 64;
            float d = fmaf(-2.f, srow[code], c2s[code]);
            if (d < best) { best = d; bidx = code; }
        }
        #pragma unroll
        for (int off = 32; off > 0; off >>= 1) {
            float ob = __shfl_down(best, off);
            int   oi = __shfl_down(bidx, off);
            if (ob < best || (ob == best && oi < bidx)) { best = ob; bidx = oi; }
        }
        bidx = __shfl(bidx, 0);

        long base = (long)row * 128 + lane * 2;
        float2 r = *reinterpret_cast<const float2*>(src + base);
        float2 q = *reinterpret_cast<const float2*>(cb + (long)bidx * 128 + lane * 2);
        float dx = r.x - q.x, dy = r.y - q.y;
        myloss += dx * dx + dy * dy;
        float2 nr; nr.x = dx; nr.y = dy;
        *reinterpret_cast<float2*>(resid + base) = nr;
        if (first) {
            float2 qv; qv.x = q.x; qv.y = q.y;
            *reinterpret_cast<float2*>(xq + base) = qv;
        } else {
            float2 xv = *reinterpret_cast<float2*>(xq + base);
            xv.x += q.x; xv.y += q.y;
            *reinterpret_cast<float2*>(xq + base) = xv;
        }
    }

    #pragma unroll
    for (int off = 32; off > 0; off >>= 1) myloss += __shfl_down(myloss, off);
    if (lane == 0) lsum[wave] = myloss;
    __syncthreads();
    if (tid == 0) atomicAdd(lossF, (lsum[0] + lsum[1]) + (lsum[2] + lsum[3]));
}

__global__ void zero4_kernel(float* __restrict__ F)
{
    if (threadIdx.x < 4) F[threadIdx.x] = 0.f;
}

__global__ void finalize_loss_kernel(const float* __restrict__ F, float* __restrict__ out)
{
    if (threadIdx.x == 0) {
        float s = (F[0] + F[1]) + (F[2] + F[3]);
        out[0] = s * (1.25f / (4.f * 65536.f * 128.f));
    }
}

extern "C" void kernel_launch(void* const* d_in, const int* in_sizes, int n_in,
                              void* d_out, int out_size, void* d_ws, size_t ws_size,
                              hipStream_t stream)
{
    const float* x      = (const float*)d_in[0];
    const float* enc_w0 = (const float*)d_in[1];
    const float* enc_b0 = (const float*)d_in[2];
    const float* enc_w1 = (const float*)d_in[3];
    const float* enc_b1 = (const float*)d_in[4];
    const float* enc_w2 = (const float*)d_in[5];
    const float* enc_b2 = (const float*)d_in[6];
    const float* dec_w0 = (const float*)d_in[7];
    const float* dec_b0 = (const float*)d_in[8];
    const float* dec_w1 = (const float*)d_in[9];
    const float* dec_b1 = (const float*)d_in[10];
    const float* dec_w2 = (const float*)d_in[11];
    const float* dec_b2 = (const float*)d_in[12];
    const float* codebooks = (const float*)d_in[13];

    const int M = 65536;
    float* ws   = (float*)d_ws;

    // Workspace overlay (201.3 MB total, same budget as proven round 1):
    //   bufA: enc h1 -> {z, resid, xq} -> dec h2
    //   bufB: enc h2 -> scores -> dec h1 -> dec_w2 split
    float* bufA   = ws;
    float* bufB   = ws + 33554432;
    float* z      = bufA;
    float* resid  = bufA + 8388608;
    float* xq     = bufA + 16777216;
    float* scores = bufB;
    float* y      = (float*)d_out;

    // Weight-split scratch lives in d_out (free until dec2 writes y).
    F16* e0h = (F16*)d_out;          F16* e0l = e0h + 393216;
    F16* e1h = e0l + 393216;         F16* e1l = e1h + 131072;
    F16* e2h = e1l + 131072;         F16* e2l = e2h + 32768;
    F16* d0h = e2l + 32768;          F16* d0l = d0h + 32768;
    F16* d1h = d0l + 32768;          F16* d1l = d1h + 131072;
    F16* cbh = d1l + 131072;         F16* cbl = cbh + 131072;
    float* F = (float*)d_out + 2000000;          // loss accum (consumed pre-decoder)
    F16* d2h = (F16*)bufB;           F16* d2l = d2h + 393216;  // prepped post-dec1

    dim3 blk(256);

    wprep_kernel<<<dim3(1536), blk, 0, stream>>>(enc_w0, e0h, e0l, 768, 512);
    wprep_kernel<<<dim3(512),  blk, 0, stream>>>(enc_w1, e1h, e1l, 512, 256);
    wprep_kernel<<<dim3(128),  blk, 0, stream>>>(enc_w2, e2h, e2l, 256, 128);
    wprep_kernel<<<dim3(128),  blk, 0, stream>>>(dec_w0, d0h, d0l, 128, 256);
    wprep_kernel<<<dim3(512),  blk, 0, stream>>>(dec_w1, d1h, d1l, 256, 512);
    cbprep_kernel<<<dim3(512), blk, 0, stream>>>(codebooks, cbh, cbl);
    zero4_kernel<<<dim3(1), dim3(64), 0, stream>>>(F);

    // ---- encoder ----
    f16gemm_kernel<true,  true><<<dim3(512, 4), blk, 0, stream>>>(x,    e0h, e0l, enc_b0, bufA, M, 512, 768);
    f16gemm_kernel<true,  true><<<dim3(512, 2), blk, 0, stream>>>(bufA, e1h, e1l, enc_b1, bufB, M, 256, 512);
    f16gemm_kernel<false, true><<<dim3(512, 1), blk, 0, stream>>>(bufB, e2h, e2l, enc_b2, z,    M, 128, 256);

    // ---- residual quantization (4 levels) ----
    for (int l = 0; l < 4; l++) {
        const float* cb  = codebooks + (long)l * 32768;
        const float* src = (l == 0) ? z : resid;
        f16gemm_kernel<false, false><<<dim3(512, 2), blk, 0, stream>>>(src, cbh + l * 32768, cbl + l * 32768,
                                                                       nullptr, scores, M, 256, 128);
        rq_update_kernel<<<dim3(1024), blk, 0, stream>>>(scores, cb, src, resid, xq, F + l, M, (l == 0) ? 1 : 0);
    }
    finalize_loss_kernel<<<dim3(1), dim3(64), 0, stream>>>(F, y + 50331648);

    // ---- decoder (y_q == x_q numerically) ----
    f16gemm_kernel<true,  true><<<dim3(512, 2), blk, 0, stream>>>(xq,   d0h, d0l, dec_b0, bufB, M, 256, 128);
    f16gemm_kernel<true,  true><<<dim3(512, 4), blk, 0, stream>>>(bufB, d1h, d1l, dec_b1, bufA, M, 512, 256);
    wprep_kernel<<<dim3(1536), blk, 0, stream>>>(dec_w2, d2h, d2l, 512, 768);
    f16gemm_kernel<false, true><<<dim3(512, 6), blk, 0, stream>>>(bufA, d2h, d2l, dec_b2, y,    M, 768, 512);
}